// Round 1
// baseline (264.729 us; speedup 1.0000x reference)
//
#include <hip/hip_runtime.h>

#define BB 8
#define NN 1024
#define DIN 64
#define DOUT 64
#define EMB 16
#define DPC 16

// ---------------- Kernel A: sim = softmax_rows(relu(E E^T)) ----------------
__global__ __launch_bounds__(256) void k_sim(const float* __restrict__ E,
                                             float* __restrict__ sim) {
    const int i = blockIdx.x;
    const int tid = threadIdx.x;
    __shared__ float rbuf[NN];
    __shared__ float red[256];

    float4 ei0 = *(const float4*)&E[i*EMB + 0];
    float4 ei1 = *(const float4*)&E[i*EMB + 4];
    float4 ei2 = *(const float4*)&E[i*EMB + 8];
    float4 ei3 = *(const float4*)&E[i*EMB + 12];

    float rv[4];
    float tmax = -1e30f;
    #pragma unroll
    for (int k = 0; k < 4; ++k) {
        int j = tid + k*256;
        float4 a0 = *(const float4*)&E[j*EMB + 0];
        float4 a1 = *(const float4*)&E[j*EMB + 4];
        float4 a2 = *(const float4*)&E[j*EMB + 8];
        float4 a3 = *(const float4*)&E[j*EMB + 12];
        float s = ei0.x*a0.x + ei0.y*a0.y + ei0.z*a0.z + ei0.w*a0.w
                + ei1.x*a1.x + ei1.y*a1.y + ei1.z*a1.z + ei1.w*a1.w
                + ei2.x*a2.x + ei2.y*a2.y + ei2.z*a2.z + ei2.w*a2.w
                + ei3.x*a3.x + ei3.y*a3.y + ei3.z*a3.z + ei3.w*a3.w;
        s = fmaxf(s, 0.0f);
        rv[k] = s;
        tmax = fmaxf(tmax, s);
    }
    red[tid] = tmax;
    __syncthreads();
    for (int s = 128; s > 0; s >>= 1) {
        if (tid < s) red[tid] = fmaxf(red[tid], red[tid + s]);
        __syncthreads();
    }
    float rmax = red[0];
    __syncthreads();

    float tsum = 0.0f;
    #pragma unroll
    for (int k = 0; k < 4; ++k) {
        float e = __expf(rv[k] - rmax);
        rbuf[tid + k*256] = e;
        tsum += e;
    }
    red[tid] = tsum;
    __syncthreads();
    for (int s = 128; s > 0; s >>= 1) {
        if (tid < s) red[tid] += red[tid + s];
        __syncthreads();
    }
    float inv = 1.0f / red[0];
    #pragma unroll
    for (int k = 0; k < 4; ++k)
        sim[i*NN + tid + k*256] = rbuf[tid + k*256] * inv;
}

// ------------- Kernel B: Z[b,c] = sum_j exp(-L1(pa[c],pa[j])); xz = x / Z -------------
__global__ __launch_bounds__(256) void k_z_xz(const float* __restrict__ pa,
                                              const float* __restrict__ x,
                                              float* __restrict__ xz) {
    const int b  = blockIdx.y;
    const int c0 = blockIdx.x * 64;
    const int tid = threadIdx.x;
    __shared__ float pa_l[512 * DPC];   // 32 KB, half the nodes at a time
    __shared__ float zpart[4][64];
    __shared__ float invZ[64];

    const int cs = tid & 63, jq = tid >> 6;
    float myc[DPC];
    #pragma unroll
    for (int p = 0; p < DPC; ++p) myc[p] = pa[b*NN*DPC + (c0 + cs)*DPC + p];

    float part = 0.0f;
    for (int h = 0; h < 2; ++h) {
        __syncthreads();
        for (int idx = tid; idx < 512*DPC/4; idx += 256)
            ((float4*)pa_l)[idx] = ((const float4*)(pa + b*NN*DPC + h*512*DPC))[idx];
        __syncthreads();
        for (int jj = jq*128; jj < jq*128 + 128; ++jj) {
            float s = 0.0f;
            #pragma unroll
            for (int p = 0; p < DPC; ++p) s += fabsf(myc[p] - pa_l[jj*DPC + p]);
            part += __expf(-s);
        }
    }
    zpart[jq][cs] = part;
    __syncthreads();
    if (tid < 64) {
        float z = zpart[0][tid] + zpart[1][tid] + zpart[2][tid] + zpart[3][tid];
        invZ[tid] = 1.0f / z;
    }
    __syncthreads();
    for (int idx = tid; idx < 64*DIN; idx += 256) {
        int c = idx >> 6, d = idx & 63;
        xz[b*NN*DIN + (c0 + c)*DIN + d] = x[b*NN*DIN + (c0 + c)*DIN + d] * invZ[c];
    }
}

// ------------- Kernel C: sx[b,m,:] = sum_c exp(-L1(pa[m],pa[c])) * xz[b,c,:] -------------
__global__ __launch_bounds__(256) void k_sx(const float* __restrict__ pa,
                                            const float* __restrict__ xz,
                                            float* __restrict__ sx) {
    const int b  = blockIdx.y;
    const int m0 = blockIdx.x * 32;
    const int tid = threadIdx.x;
    __shared__ __align__(16) float pa_m[32 * 20];
    __shared__ __align__(16) float pa_c[64 * 20];
    __shared__ __align__(16) float wt[32 * 68];
    __shared__ __align__(16) float xz_t[64 * 64];

    // stage pa rows for this m-tile (pad stride 20 keeps float4 alignment + banks spread)
    for (int idx = tid; idx < 32*4; idx += 256) {
        int node = idx >> 2, p4 = idx & 3;
        *(float4*)&pa_m[node*20 + p4*4] =
            ((const float4*)(pa + b*NN*DPC + (m0 + node)*DPC))[p4];
    }
    const int m = tid >> 3, dg = tid & 7;
    float acc[8];
    #pragma unroll
    for (int k = 0; k < 8; ++k) acc[k] = 0.0f;

    for (int ct = 0; ct < 16; ++ct) {
        __syncthreads();
        for (int idx = tid; idx < 64*4; idx += 256) {
            int node = idx >> 2, p4 = idx & 3;
            *(float4*)&pa_c[node*20 + p4*4] =
                ((const float4*)(pa + b*NN*DPC + (ct*64 + node)*DPC))[p4];
        }
        for (int idx = tid; idx < 64*64/4; idx += 256)
            ((float4*)xz_t)[idx] = ((const float4*)(xz + b*NN*DIN + ct*64*DIN))[idx];
        __syncthreads();

        // compute w[m,c] = exp(-L1) for this 32x64 tile
        {
            const int mm = tid >> 3, csub = tid & 7;
            #pragma unroll
            for (int jj = 0; jj < 8; ++jj) {
                int c = csub + jj*8;
                float s = 0.0f;
                #pragma unroll
                for (int p = 0; p < DPC; ++p)
                    s += fabsf(pa_m[mm*20 + p] - pa_c[c*20 + p]);
                wt[mm*68 + c] = __expf(-s);
            }
        }
        __syncthreads();

        #pragma unroll 4
        for (int cc = 0; cc < 64; ++cc) {
            float wv = wt[m*68 + cc];
            const float4 x0 = *(const float4*)&xz_t[cc*64 + dg*8];
            const float4 x1 = *(const float4*)&xz_t[cc*64 + dg*8 + 4];
            acc[0] += wv*x0.x; acc[1] += wv*x0.y; acc[2] += wv*x0.z; acc[3] += wv*x0.w;
            acc[4] += wv*x1.x; acc[5] += wv*x1.y; acc[6] += wv*x1.z; acc[7] += wv*x1.w;
        }
    }
    float* dst = sx + b*NN*DIN + (m0 + m)*DIN + dg*8;
    *(float4*)dst       = make_float4(acc[0], acc[1], acc[2], acc[3]);
    *(float4*)(dst + 4) = make_float4(acc[4], acc[5], acc[6], acc[7]);
}

// ------------- Kernel D: y[b] = sim @ sx[b] -------------
__global__ __launch_bounds__(256) void k_y(const float* __restrict__ sim,
                                           const float* __restrict__ sx,
                                           float* __restrict__ y) {
    const int b  = blockIdx.y;
    const int n0 = blockIdx.x * 32;
    const int tid = threadIdx.x;
    __shared__ __align__(16) float st[32 * 68];
    __shared__ __align__(16) float sxt[64 * 64];

    const int m = tid >> 3, dg = tid & 7;
    float acc[8];
    #pragma unroll
    for (int k = 0; k < 8; ++k) acc[k] = 0.0f;

    for (int mt = 0; mt < 16; ++mt) {
        __syncthreads();
        for (int idx = tid; idx < 512; idx += 256) {
            int row = idx >> 4, c4 = idx & 15;
            *(float4*)&st[row*68 + c4*4] =
                *(const float4*)&sim[(n0 + row)*NN + mt*64 + c4*4];
        }
        for (int idx = tid; idx < 64*64/4; idx += 256)
            ((float4*)sxt)[idx] = ((const float4*)(sx + b*NN*DIN + mt*64*DIN))[idx];
        __syncthreads();

        #pragma unroll 4
        for (int cc = 0; cc < 64; ++cc) {
            float wv = st[m*68 + cc];
            const float4 x0 = *(const float4*)&sxt[cc*64 + dg*8];
            const float4 x1 = *(const float4*)&sxt[cc*64 + dg*8 + 4];
            acc[0] += wv*x0.x; acc[1] += wv*x0.y; acc[2] += wv*x0.z; acc[3] += wv*x0.w;
            acc[4] += wv*x1.x; acc[5] += wv*x1.y; acc[6] += wv*x1.z; acc[7] += wv*x1.w;
        }
    }
    float* dst = y + b*NN*DIN + (n0 + m)*DIN + dg*8;
    *(float4*)dst       = make_float4(acc[0], acc[1], acc[2], acc[3]);
    *(float4*)(dst + 4) = make_float4(acc[4], acc[5], acc[6], acc[7]);
}

// ------------- Kernel E: out[b,n,o] = sum_i v[b,n,i] W'[n,i,o] + bias[n,o] -------------
// v = [sx ; y] (i in 0..127), W'[n,i,o] = sum_d E[n,d] wp[d, i>>6, i&63, o]
// Block handles 4 nodes; W' generated per 8-i chunk in LDS from a staged wp chunk.
#define NSTRIDE 516   // 8*64 + 4 : breaks nsub bank aliasing, keeps 16B alignment
__global__ __launch_bounds__(256) void k_out(const float* __restrict__ E,
                                             const float* __restrict__ wp,
                                             const float* __restrict__ bp,
                                             const float* __restrict__ sx,
                                             const float* __restrict__ y,
                                             float* __restrict__ out) {
    const int n0 = blockIdx.x * 4;
    const int tid = threadIdx.x;
    __shared__ __align__(16) float wpch[16 * 8 * 64];      // 32 KB: wp[d, i-chunk, o]
    __shared__ __align__(16) float Wl[4 * NSTRIDE];        // per-node W' chunk
    __shared__ float vch[32 * 8];
    __shared__ float El[4 * 16];

    if (tid < 64) El[tid] = E[n0*EMB + tid];   // [nsub*16 + d]

    const int bn = tid >> 3, og = tid & 7;
    const int b = bn >> 2, nsub = bn & 3;
    float acc[8];
    #pragma unroll
    for (int k = 0; k < 8; ++k) acc[k] = 0.0f;

    for (int ic = 0; ic < 16; ++ic) {
        __syncthreads();
        // stage wp chunk: all d, i = ic*8..ic*8+7, all o  (as float4)
        for (int idx = tid; idx < 2048; idx += 256) {
            int d = idx >> 7, isub = (idx >> 4) & 7, o4 = idx & 15;
            int gi = ic*8 + isub;
            int k = gi >> 6, i0 = gi & 63;
            ((float4*)wpch)[idx] = ((const float4*)wp)[((d*2 + k)*64 + i0)*16 + o4];
        }
        // stage v chunk: v[b, n, ic*8 + isub]
        {
            int vbn = tid >> 3, visub = tid & 7;
            int vb = vbn >> 2, vns = vbn & 3;
            int nidx = (vb*NN + (n0 + vns))*DIN;
            float val;
            if (ic < 8) val = sx[nidx + ic*8 + visub];
            else        val = y[nidx + (ic - 8)*8 + visub];
            vch[vbn*8 + visub] = val;
        }
        __syncthreads();
        // W' chunk: Wl[nsub, isub, o] = sum_d El[nsub,d] * wpch[d, isub, o]
        for (int e = tid; e < 512; e += 256) {
            int ns = e >> 7, isub = (e >> 4) & 7, o4 = e & 15;
            float4 s = make_float4(0.f, 0.f, 0.f, 0.f);
            #pragma unroll
            for (int d = 0; d < EMB; ++d) {
                float ev = El[ns*16 + d];
                const float4 w = *(const float4*)&wpch[(d*8 + isub)*64 + o4*4];
                s.x += ev*w.x; s.y += ev*w.y; s.z += ev*w.z; s.w += ev*w.w;
            }
            *(float4*)&Wl[ns*NSTRIDE + isub*64 + o4*4] = s;
        }
        __syncthreads();
        #pragma unroll
        for (int isub = 0; isub < 8; ++isub) {
            float wv = vch[bn*8 + isub];
            const float4 w0 = *(const float4*)&Wl[nsub*NSTRIDE + isub*64 + og*8];
            const float4 w1 = *(const float4*)&Wl[nsub*NSTRIDE + isub*64 + og*8 + 4];
            acc[0] += wv*w0.x; acc[1] += wv*w0.y; acc[2] += wv*w0.z; acc[3] += wv*w0.w;
            acc[4] += wv*w1.x; acc[5] += wv*w1.y; acc[6] += wv*w1.z; acc[7] += wv*w1.w;
        }
    }
    // bias + store
    float4 bv0 = make_float4(0.f, 0.f, 0.f, 0.f);
    float4 bv1 = make_float4(0.f, 0.f, 0.f, 0.f);
    #pragma unroll
    for (int d = 0; d < EMB; ++d) {
        float ev = El[nsub*16 + d];
        const float4 p0 = *(const float4*)&bp[d*DOUT + og*8];
        const float4 p1 = *(const float4*)&bp[d*DOUT + og*8 + 4];
        bv0.x += ev*p0.x; bv0.y += ev*p0.y; bv0.z += ev*p0.z; bv0.w += ev*p0.w;
        bv1.x += ev*p1.x; bv1.y += ev*p1.y; bv1.z += ev*p1.z; bv1.w += ev*p1.w;
    }
    float* dst = out + (b*NN + (n0 + nsub))*DOUT + og*8;
    *(float4*)dst       = make_float4(acc[0]+bv0.x, acc[1]+bv0.y, acc[2]+bv0.z, acc[3]+bv0.w);
    *(float4*)(dst + 4) = make_float4(acc[4]+bv1.x, acc[5]+bv1.y, acc[6]+bv1.z, acc[7]+bv1.w);
}

extern "C" void kernel_launch(void* const* d_in, const int* in_sizes, int n_in,
                              void* d_out, int out_size, void* d_ws, size_t ws_size,
                              hipStream_t stream) {
    (void)in_sizes; (void)n_in; (void)out_size; (void)ws_size;
    const float* x  = (const float*)d_in[0];
    const float* E  = (const float*)d_in[1];
    const float* pa = (const float*)d_in[2];
    const float* wp = (const float*)d_in[3];
    const float* bp = (const float*)d_in[4];
    float* out = (float*)d_out;

    float* ws  = (float*)d_ws;
    float* sim = ws;                       // N*N            = 1,048,576 floats
    float* xz  = sim + NN*NN;              // B*N*DIN        =   524,288
    float* sx  = xz + BB*NN*DIN;           //                =   524,288
    float* y   = sx + BB*NN*DIN;           //                =   524,288

    k_sim<<<NN, 256, 0, stream>>>(E, sim);
    k_z_xz<<<dim3(16, BB), 256, 0, stream>>>(pa, x, xz);
    k_sx<<<dim3(32, BB), 256, 0, stream>>>(pa, xz, sx);
    k_y<<<dim3(32, BB), 256, 0, stream>>>(sim, sx, y);
    k_out<<<NN/4, 256, 0, stream>>>(E, wp, bp, sx, y, out);
}